// Round 6
// baseline (343.803 us; speedup 1.0000x reference)
//
#include <hip/hip_runtime.h>
#include <hip/hip_bf16.h>
#include <stdint.h>

#define D_DIM 1024
#define B_DIM 8
#define S_DIM 1024
#define NBLK  512            // persistent grid: 512 blocks x 256 thd, co-resident
                             // (32 KB LDS -> 5 blk/CU cap, VGPR ~76 -> plenty; need 2)

typedef __bf16 bf16;
typedef __bf16 bf16x4 __attribute__((ext_vector_type(4)));
typedef __bf16 bf16x8 __attribute__((ext_vector_type(8)));
typedef float floatx4 __attribute__((ext_vector_type(4)));

__device__ __forceinline__ void async_copy16(const void* g, void* l) {
    __builtin_amdgcn_global_load_lds(
        (const __attribute__((address_space(1))) void*)g,
        (__attribute__((address_space(3))) void*)l, 16, 0, 0);
}

// Device-scope grid barrier: one arrive per block (agent-scope RMW), tid0
// spins on agent-scope acquire load; __syncthreads + threadfence propagate
// visibility to all lanes. Counters are distinct per use (no sense reversal).
__device__ __forceinline__ void grid_barrier(int* cnt) {
    __syncthreads();
    if (threadIdx.x == 0) {
        __hip_atomic_fetch_add(cnt, 1, __ATOMIC_ACQ_REL, __HIP_MEMORY_SCOPE_AGENT);
        while (__hip_atomic_load(cnt, __ATOMIC_ACQUIRE, __HIP_MEMORY_SCOPE_AGENT) < NBLK)
            __builtin_amdgcn_s_sleep(2);
    }
    __syncthreads();
    __threadfence();   // agent-scope acquire for all lanes (XCD-L2 refresh)
}

union SmemU {
    struct { bf16 As[128 * 64]; bf16 Bs[128 * 64]; } g;   // 32 KB GEMM tiles
    float t[32][33];                                       // prep transpose tile
};

// ---------------------------------------------------------------------------
// GEMM tile body (R4's measured config): 128x128 tile, BK=64, 4 waves (2x2),
// 16x16x32 bf16 MFMA, width-16 global_load_lds, XOR-swizzled granules.
// EPI=0: bf16 store (tmp). EPI=1: fp32 + s_row + s_col + bias, nontemporal.
// ---------------------------------------------------------------------------
template <int EPI>
__device__ __forceinline__ void gemm_tile(
    const bf16* __restrict__ Ab, const bf16* __restrict__ Bb,
    SmemU* sm, void* __restrict__ Cout, int N, int row0, int col0,
    const float* __restrict__ srow, const float* __restrict__ scol,
    float b0)
{
    const int BK = 64;
    int tid  = threadIdx.x;
    int wid  = tid >> 6;
    int lane = tid & 63;
    int quad = lane >> 4;
    int l16  = lane & 15;
    int wr   = wid >> 1;
    int wc   = wid & 1;

    floatx4 zero = {0.0f, 0.0f, 0.0f, 0.0f};
    floatx4 acc[4][4];
    #pragma unroll
    for (int i = 0; i < 4; ++i)
        #pragma unroll
        for (int j = 0; j < 4; ++j) acc[i][j] = zero;

    bf16* As = sm->g.As;
    bf16* Bs = sm->g.Bs;

    for (int k0 = 0; k0 < D_DIM; k0 += BK) {
        #pragma unroll
        for (int it = 0; it < 4; ++it) {
            int g  = wid * 256 + it * 64 + lane;
            int r  = g >> 3;
            int cg = (g & 7) ^ (r & 7);
            int ldsoff = (wid * 256 + it * 64) * 8;
            async_copy16(Ab + (size_t)r * D_DIM + k0 + cg * 8, &As[ldsoff]);
            async_copy16(Bb + (size_t)r * D_DIM + k0 + cg * 8, &Bs[ldsoff]);
        }
        __syncthreads();

        #pragma unroll
        for (int kk = 0; kk < BK; kk += 32) {
            bf16x8 a[4], b[4];
            #pragma unroll
            for (int mt = 0; mt < 4; ++mt) {
                int row  = wr * 64 + mt * 16 + l16;
                int slot = ((kk >> 3) + quad) ^ (row & 7);
                a[mt] = *(const bf16x8*)&As[row * BK + slot * 8];
            }
            #pragma unroll
            for (int nt = 0; nt < 4; ++nt) {
                int row  = wc * 64 + nt * 16 + l16;
                int slot = ((kk >> 3) + quad) ^ (row & 7);
                b[nt] = *(const bf16x8*)&Bs[row * BK + slot * 8];
            }
            #pragma unroll
            for (int mt = 0; mt < 4; ++mt)
                #pragma unroll
                for (int nt = 0; nt < 4; ++nt)
                    acc[mt][nt] = __builtin_amdgcn_mfma_f32_16x16x32_bf16(
                        a[mt], b[nt], acc[mt][nt], 0, 0, 0);
        }
        __syncthreads();
    }

    int r0 = row0 + wr * 64;
    int c0 = col0 + wc * 64;
    if (EPI == 0) {
        bf16* Cb = (bf16*)Cout;
        #pragma unroll
        for (int mt = 0; mt < 4; ++mt)
            #pragma unroll
            for (int r = 0; r < 4; ++r) {
                int row = r0 + mt * 16 + quad * 4 + r;
                #pragma unroll
                for (int nt = 0; nt < 4; ++nt) {
                    int col = c0 + nt * 16 + l16;
                    Cb[(size_t)row * N + col] = (bf16)acc[mt][nt][r];
                }
            }
    } else {
        float* Cf = (float*)Cout;
        #pragma unroll
        for (int mt = 0; mt < 4; ++mt)
            #pragma unroll
            for (int r = 0; r < 4; ++r) {
                int row = r0 + mt * 16 + quad * 4 + r;
                float sh = srow[row] + b0;
                #pragma unroll
                for (int nt = 0; nt < 4; ++nt) {
                    int col = c0 + nt * 16 + l16;
                    __builtin_nontemporal_store(acc[mt][nt][r] + sh + scol[col],
                                                &Cf[(size_t)row * N + col]);
                }
            }
    }
}

// ---------------------------------------------------------------------------
// Fused persistent kernel: P0 prep -> barrier -> P1 GEMM1 -> barrier -> P2
// ---------------------------------------------------------------------------
__global__ __launch_bounds__(256, 2) void fused_kernel(
    const float* __restrict__ head, const float* __restrict__ dep,
    const float* __restrict__ U, const float* __restrict__ edge_W,
    const float* __restrict__ edge_b,
    bf16* __restrict__ head_b, bf16* __restrict__ dep_b,
    bf16* __restrict__ Ut, bf16* __restrict__ tmp_b,
    float* __restrict__ s_head, float* __restrict__ s_dep,
    float* __restrict__ out, int* __restrict__ cnt)
{
    __shared__ SmemU sm;
    int blk = blockIdx.x;

    // ---------------- P0: prep (grid-stride over 5120 units) ----------------
    for (int u = blk; u < 5120; u += NBLK) {
        if (u < 4096) {
            // cast + projection: 4 rows, one wave each
            int wid  = threadIdx.x >> 6;
            int lane = threadIdx.x & 63;
            int row  = u * 4 + wid;
            const float* src;
            bf16* dst;
            const float* w;
            float* sout;
            if (row < B_DIM * S_DIM) {
                src  = head   + (size_t)row * D_DIM;
                dst  = head_b + (size_t)row * D_DIM;
                w    = edge_W;
                sout = s_head + row;
            } else {
                int r = row - B_DIM * S_DIM;
                src  = dep   + (size_t)r * D_DIM;
                dst  = dep_b + (size_t)r * D_DIM;
                w    = edge_W + D_DIM;
                sout = s_dep + r;
            }
            float d = 0.0f;
            #pragma unroll
            for (int it = 0; it < 4; ++it) {
                int idx = it * 64 + lane;
                float4 v  = ((const float4*)src)[idx];
                float4 wv = ((const float4*)w)[idx];
                bf16x4 o;
                o[0] = (bf16)v.x; o[1] = (bf16)v.y;
                o[2] = (bf16)v.z; o[3] = (bf16)v.w;
                ((bf16x4*)dst)[idx] = o;
                d += v.x * wv.x + v.y * wv.y + v.z * wv.z + v.w * wv.w;
            }
            #pragma unroll
            for (int off = 32; off > 0; off >>= 1)
                d += __shfl_down(d, off, 64);
            if (lane == 0) *sout = d;
        } else {
            // transpose + cast U: 32x32 tile
            int t  = u - 4096;
            int bx = (t & 31) * 32;
            int by = (t >> 5) * 32;
            int tx = threadIdx.x & 31;
            int ty4 = (threadIdx.x >> 5) * 4;
            __syncthreads();   // protect sm.t from previous unit's readers
            #pragma unroll
            for (int i = 0; i < 4; ++i)
                sm.t[ty4 + i][tx] = U[(size_t)(by + ty4 + i) * D_DIM + bx + tx];
            __syncthreads();
            #pragma unroll
            for (int i = 0; i < 4; ++i)
                Ut[(size_t)(bx + ty4 + i) * D_DIM + by + tx] = (bf16)sm.t[tx][ty4 + i];
        }
    }

    grid_barrier(&cnt[0]);

    // ---------------- P1: tmp = head_b @ Ut^T  (512 tiles, 1/block) --------
    {
        int bx = blk & 7;          // N-tile (D/128 = 8)
        int by = blk >> 3;         // M-tile (8192/128 = 64)
        gemm_tile<0>(head_b + (size_t)by * 128 * D_DIM,
                     Ut     + (size_t)bx * 128 * D_DIM,
                     &sm, tmp_b, D_DIM, by * 128, bx * 128,
                     nullptr, nullptr, 0.0f);
    }

    grid_barrier(&cnt[1]);

    // ---------------- P2: out = tmp @ dep^T + s_head + s_dep + bias --------
    {
        int bz = blk >> 6;         // batch (8)
        int t  = blk & 63;
        int bx = t & 7;            // j-tile
        int by = t >> 3;           // i-tile
        const size_t SD = (size_t)S_DIM * D_DIM;
        gemm_tile<1>(tmp_b + bz * SD + (size_t)by * 128 * D_DIM,
                     dep_b + bz * SD + (size_t)bx * 128 * D_DIM,
                     &sm, out + (size_t)bz * S_DIM * S_DIM, S_DIM,
                     by * 128, bx * 128,
                     s_head + bz * S_DIM, s_dep + bz * S_DIM, edge_b[0]);
    }
}

// ---------------------------------------------------------------------------
extern "C" void kernel_launch(void* const* d_in, const int* in_sizes, int n_in,
                              void* d_out, int out_size, void* d_ws, size_t ws_size,
                              hipStream_t stream) {
    const float* head   = (const float*)d_in[0];
    const float* dep    = (const float*)d_in[1];
    const float* edge_U = (const float*)d_in[2];
    const float* edge_W = (const float*)d_in[3];
    const float* edge_b = (const float*)d_in[4];
    float* out = (float*)d_out;

    char* ws = (char*)d_ws;
    const size_t nBSD = (size_t)B_DIM * S_DIM * D_DIM;

    bf16*  head_b = (bf16*)ws;  ws += nBSD * sizeof(bf16);                   // 16 MB
    bf16*  dep_b  = (bf16*)ws;  ws += nBSD * sizeof(bf16);                   // 16 MB
    bf16*  Ut     = (bf16*)ws;  ws += (size_t)D_DIM * D_DIM * sizeof(bf16);  // 2 MB
    bf16*  tmp_b  = (bf16*)ws;  ws += nBSD * sizeof(bf16);                   // 16 MB
    float* s_head = (float*)ws; ws += (size_t)B_DIM * S_DIM * sizeof(float);
    float* s_dep  = (float*)ws; ws += (size_t)B_DIM * S_DIM * sizeof(float);

    int* cnt = (int*)((char*)d_ws + (size_t)64 * 1024 * 1024);   // past buffers
    hipMemsetAsync(cnt, 0, 64, stream);                          // zero barrier ctrs

    fused_kernel<<<NBLK, 256, 0, stream>>>(
        head, dep, edge_U, edge_W, edge_b,
        head_b, dep_b, Ut, tmp_b, s_head, s_dep, out, cnt);
}

// Round 7
// 318.496 us; speedup vs baseline: 1.0795x; 1.0795x over previous
//
#include <hip/hip_runtime.h>
#include <hip/hip_bf16.h>
#include <stdint.h>

#define D_DIM 1024
#define B_DIM 8
#define S_DIM 1024
#define NBLK  512            // persistent grid: 512 blocks x 256 thd, co-resident
                             // (32 KB LDS -> 5 blk/CU cap; VGPR ~68; need 2/CU)

typedef __bf16 bf16;
typedef __bf16 bf16x4 __attribute__((ext_vector_type(4)));
typedef __bf16 bf16x8 __attribute__((ext_vector_type(8)));
typedef float floatx4 __attribute__((ext_vector_type(4)));

__device__ __forceinline__ void async_copy16(const void* g, void* l) {
    __builtin_amdgcn_global_load_lds(
        (const __attribute__((address_space(1))) void*)g,
        (__attribute__((address_space(3))) void*)l, 16, 0, 0);
}

// Grid barrier, R7 fix: the R6 version polled with ACQUIRE, which emits a
// buffer_inv (L1+L2 invalidate) EVERY iteration -> 512 spinners continuously
// nuked the device's caches while stragglers computed (260 us, 1 TB/s, 5%
// MfmaUtil). Now: RELEASE on arrive (one dirty-L2 flush per block), RELAXED
// polls (agent-scope relaxed load bypasses L1/L2 via sc0 sc1 -> fresh value,
// NO invalidate), one ACQUIRE load after the spin, then block-wide
// __threadfence for stale-line invalidation (as in R6, which was correct).
__device__ __forceinline__ void grid_barrier(int* cnt) {
    __syncthreads();
    if (threadIdx.x == 0) {
        __hip_atomic_fetch_add(cnt, 1, __ATOMIC_RELEASE, __HIP_MEMORY_SCOPE_AGENT);
        while (__hip_atomic_load(cnt, __ATOMIC_RELAXED, __HIP_MEMORY_SCOPE_AGENT) < NBLK)
            __builtin_amdgcn_s_sleep(4);
        (void)__hip_atomic_load(cnt, __ATOMIC_ACQUIRE, __HIP_MEMORY_SCOPE_AGENT);
    }
    __syncthreads();
    __threadfence();   // per-thread acquire: invalidate stale L1/L2 lines
}

union SmemU {
    struct { bf16 As[128 * 64]; bf16 Bs[128 * 64]; } g;   // 32 KB GEMM tiles
    float t[32][33];                                       // prep transpose tile
};

// ---------------------------------------------------------------------------
// GEMM tile body (R4 config): 128x128 tile, BK=64, 4 waves (2x2),
// 16x16x32 bf16 MFMA, width-16 global_load_lds, XOR-swizzled granules.
// EPI=0: bf16 store (tmp). EPI=1: fp32 + s_row + s_col + bias, nontemporal.
// ---------------------------------------------------------------------------
template <int EPI>
__device__ __forceinline__ void gemm_tile(
    const bf16* __restrict__ Ab, const bf16* __restrict__ Bb,
    SmemU* sm, void* __restrict__ Cout, int N, int row0, int col0,
    const float* __restrict__ srow, const float* __restrict__ scol,
    float b0)
{
    const int BK = 64;
    int tid  = threadIdx.x;
    int wid  = tid >> 6;
    int lane = tid & 63;
    int quad = lane >> 4;
    int l16  = lane & 15;
    int wr   = wid >> 1;
    int wc   = wid & 1;

    floatx4 zero = {0.0f, 0.0f, 0.0f, 0.0f};
    floatx4 acc[4][4];
    #pragma unroll
    for (int i = 0; i < 4; ++i)
        #pragma unroll
        for (int j = 0; j < 4; ++j) acc[i][j] = zero;

    bf16* As = sm->g.As;
    bf16* Bs = sm->g.Bs;

    for (int k0 = 0; k0 < D_DIM; k0 += BK) {
        #pragma unroll
        for (int it = 0; it < 4; ++it) {
            int g  = wid * 256 + it * 64 + lane;
            int r  = g >> 3;
            int cg = (g & 7) ^ (r & 7);
            int ldsoff = (wid * 256 + it * 64) * 8;
            async_copy16(Ab + (size_t)r * D_DIM + k0 + cg * 8, &As[ldsoff]);
            async_copy16(Bb + (size_t)r * D_DIM + k0 + cg * 8, &Bs[ldsoff]);
        }
        __syncthreads();

        #pragma unroll
        for (int kk = 0; kk < BK; kk += 32) {
            bf16x8 a[4], b[4];
            #pragma unroll
            for (int mt = 0; mt < 4; ++mt) {
                int row  = wr * 64 + mt * 16 + l16;
                int slot = ((kk >> 3) + quad) ^ (row & 7);
                a[mt] = *(const bf16x8*)&As[row * BK + slot * 8];
            }
            #pragma unroll
            for (int nt = 0; nt < 4; ++nt) {
                int row  = wc * 64 + nt * 16 + l16;
                int slot = ((kk >> 3) + quad) ^ (row & 7);
                b[nt] = *(const bf16x8*)&Bs[row * BK + slot * 8];
            }
            #pragma unroll
            for (int mt = 0; mt < 4; ++mt)
                #pragma unroll
                for (int nt = 0; nt < 4; ++nt)
                    acc[mt][nt] = __builtin_amdgcn_mfma_f32_16x16x32_bf16(
                        a[mt], b[nt], acc[mt][nt], 0, 0, 0);
        }
        __syncthreads();
    }

    int r0 = row0 + wr * 64;
    int c0 = col0 + wc * 64;
    if (EPI == 0) {
        bf16* Cb = (bf16*)Cout;
        #pragma unroll
        for (int mt = 0; mt < 4; ++mt)
            #pragma unroll
            for (int r = 0; r < 4; ++r) {
                int row = r0 + mt * 16 + quad * 4 + r;
                #pragma unroll
                for (int nt = 0; nt < 4; ++nt) {
                    int col = c0 + nt * 16 + l16;
                    Cb[(size_t)row * N + col] = (bf16)acc[mt][nt][r];
                }
            }
    } else {
        float* Cf = (float*)Cout;
        #pragma unroll
        for (int mt = 0; mt < 4; ++mt)
            #pragma unroll
            for (int r = 0; r < 4; ++r) {
                int row = r0 + mt * 16 + quad * 4 + r;
                float sh = srow[row] + b0;
                #pragma unroll
                for (int nt = 0; nt < 4; ++nt) {
                    int col = c0 + nt * 16 + l16;
                    __builtin_nontemporal_store(acc[mt][nt][r] + sh + scol[col],
                                                &Cf[(size_t)row * N + col]);
                }
            }
    }
}

// ---------------------------------------------------------------------------
// Fused persistent kernel: P0 prep -> barrier -> P1 GEMM1 -> barrier -> P2
// ---------------------------------------------------------------------------
__global__ __launch_bounds__(256, 2) void fused_kernel(
    const float* __restrict__ head, const float* __restrict__ dep,
    const float* __restrict__ U, const float* __restrict__ edge_W,
    const float* __restrict__ edge_b,
    bf16* __restrict__ head_b, bf16* __restrict__ dep_b,
    bf16* __restrict__ Ut, bf16* __restrict__ tmp_b,
    float* __restrict__ s_head, float* __restrict__ s_dep,
    float* __restrict__ out, int* __restrict__ cnt)
{
    __shared__ SmemU sm;
    int blk = blockIdx.x;

    // ---------------- P0: prep (grid-stride over 5120 units) ----------------
    for (int u = blk; u < 5120; u += NBLK) {
        if (u < 4096) {
            int wid  = threadIdx.x >> 6;
            int lane = threadIdx.x & 63;
            int row  = u * 4 + wid;
            const float* src;
            bf16* dst;
            const float* w;
            float* sout;
            if (row < B_DIM * S_DIM) {
                src  = head   + (size_t)row * D_DIM;
                dst  = head_b + (size_t)row * D_DIM;
                w    = edge_W;
                sout = s_head + row;
            } else {
                int r = row - B_DIM * S_DIM;
                src  = dep   + (size_t)r * D_DIM;
                dst  = dep_b + (size_t)r * D_DIM;
                w    = edge_W + D_DIM;
                sout = s_dep + r;
            }
            float d = 0.0f;
            #pragma unroll
            for (int it = 0; it < 4; ++it) {
                int idx = it * 64 + lane;
                float4 v  = ((const float4*)src)[idx];
                float4 wv = ((const float4*)w)[idx];
                bf16x4 o;
                o[0] = (bf16)v.x; o[1] = (bf16)v.y;
                o[2] = (bf16)v.z; o[3] = (bf16)v.w;
                ((bf16x4*)dst)[idx] = o;
                d += v.x * wv.x + v.y * wv.y + v.z * wv.z + v.w * wv.w;
            }
            #pragma unroll
            for (int off = 32; off > 0; off >>= 1)
                d += __shfl_down(d, off, 64);
            if (lane == 0) *sout = d;
        } else {
            int t  = u - 4096;
            int bx = (t & 31) * 32;
            int by = (t >> 5) * 32;
            int tx = threadIdx.x & 31;
            int ty4 = (threadIdx.x >> 5) * 4;
            __syncthreads();
            #pragma unroll
            for (int i = 0; i < 4; ++i)
                sm.t[ty4 + i][tx] = U[(size_t)(by + ty4 + i) * D_DIM + bx + tx];
            __syncthreads();
            #pragma unroll
            for (int i = 0; i < 4; ++i)
                Ut[(size_t)(bx + ty4 + i) * D_DIM + by + tx] = (bf16)sm.t[tx][ty4 + i];
        }
    }

    grid_barrier(&cnt[0]);

    // ---------------- P1: tmp = head_b @ Ut^T  (512 tiles, 1/block) --------
    {
        int bx = blk & 7;          // N-tile (D/128 = 8)
        int by = blk >> 3;         // M-tile (8192/128 = 64)
        gemm_tile<0>(head_b + (size_t)by * 128 * D_DIM,
                     Ut     + (size_t)bx * 128 * D_DIM,
                     &sm, tmp_b, D_DIM, by * 128, bx * 128,
                     nullptr, nullptr, 0.0f);
    }

    grid_barrier(&cnt[1]);

    // ---------------- P2: out = tmp @ dep^T + s_head + s_dep + bias --------
    {
        int bz = blk >> 6;         // batch (8)
        int t  = blk & 63;
        int bx = t & 7;            // j-tile
        int by = t >> 3;           // i-tile
        const size_t SD = (size_t)S_DIM * D_DIM;
        gemm_tile<1>(tmp_b + bz * SD + (size_t)by * 128 * D_DIM,
                     dep_b + bz * SD + (size_t)bx * 128 * D_DIM,
                     &sm, out + (size_t)bz * S_DIM * S_DIM, S_DIM,
                     by * 128, bx * 128,
                     s_head + bz * S_DIM, s_dep + bz * S_DIM, edge_b[0]);
    }
}

// ---------------------------------------------------------------------------
extern "C" void kernel_launch(void* const* d_in, const int* in_sizes, int n_in,
                              void* d_out, int out_size, void* d_ws, size_t ws_size,
                              hipStream_t stream) {
    const float* head   = (const float*)d_in[0];
    const float* dep    = (const float*)d_in[1];
    const float* edge_U = (const float*)d_in[2];
    const float* edge_W = (const float*)d_in[3];
    const float* edge_b = (const float*)d_in[4];
    float* out = (float*)d_out;

    char* ws = (char*)d_ws;
    const size_t nBSD = (size_t)B_DIM * S_DIM * D_DIM;

    bf16*  head_b = (bf16*)ws;  ws += nBSD * sizeof(bf16);                   // 16 MB
    bf16*  dep_b  = (bf16*)ws;  ws += nBSD * sizeof(bf16);                   // 16 MB
    bf16*  Ut     = (bf16*)ws;  ws += (size_t)D_DIM * D_DIM * sizeof(bf16);  // 2 MB
    bf16*  tmp_b  = (bf16*)ws;  ws += nBSD * sizeof(bf16);                   // 16 MB
    float* s_head = (float*)ws; ws += (size_t)B_DIM * S_DIM * sizeof(float);
    float* s_dep  = (float*)ws; ws += (size_t)B_DIM * S_DIM * sizeof(float);

    int* cnt = (int*)((char*)d_ws + (size_t)64 * 1024 * 1024);   // past buffers
    hipMemsetAsync(cnt, 0, 64, stream);                          // zero barrier ctrs

    fused_kernel<<<NBLK, 256, 0, stream>>>(
        head, dep, edge_U, edge_W, edge_b,
        head_b, dep_b, Ut, tmp_b, s_head, s_dep, out, cnt);
}

// Round 8
// 166.356 us; speedup vs baseline: 2.0667x; 1.9145x over previous
//
#include <hip/hip_runtime.h>
#include <hip/hip_bf16.h>
#include <stdint.h>

#define D_DIM 1024
#define B_DIM 8
#define S_DIM 1024

typedef __bf16 bf16;
typedef __bf16 bf16x4 __attribute__((ext_vector_type(4)));
typedef __bf16 bf16x8 __attribute__((ext_vector_type(8)));
typedef float floatx4 __attribute__((ext_vector_type(4)));

__device__ __forceinline__ void async_copy16(const void* g, void* l) {
    __builtin_amdgcn_global_load_lds(
        (const __attribute__((address_space(1))) void*)g,
        (__attribute__((address_space(3))) void*)l, 16, 0, 0);
}

// ---------------------------------------------------------------------------
// Prep kernel (fused): blocks [0,4096) cast head/dep fp32->bf16 + W-projection
// (one wave per row); blocks [4096,5120) transpose+cast U -> Ut.
// Measured at HBM BW ceiling (~16 us) — do not touch.
// ---------------------------------------------------------------------------
__global__ __launch_bounds__(256) void prep_kernel(
    const float* __restrict__ head, const float* __restrict__ dep,
    const float* __restrict__ U, const float* __restrict__ edge_W,
    bf16* __restrict__ head_b, bf16* __restrict__ dep_b,
    bf16* __restrict__ Ut,
    float* __restrict__ s_head, float* __restrict__ s_dep)
{
    int blk = blockIdx.x;
    if (blk < 4096) {
        int wid  = threadIdx.x >> 6;
        int lane = threadIdx.x & 63;
        int row  = blk * 4 + wid;

        const float* src;
        bf16* dst;
        const float* w;
        float* sout;
        if (row < B_DIM * S_DIM) {
            src  = head   + (size_t)row * D_DIM;
            dst  = head_b + (size_t)row * D_DIM;
            w    = edge_W;
            sout = s_head + row;
        } else {
            int r = row - B_DIM * S_DIM;
            src  = dep   + (size_t)r * D_DIM;
            dst  = dep_b + (size_t)r * D_DIM;
            w    = edge_W + D_DIM;
            sout = s_dep + r;
        }
        float d = 0.0f;
        #pragma unroll
        for (int it = 0; it < 4; ++it) {
            int idx = it * 64 + lane;
            float4 v  = ((const float4*)src)[idx];
            float4 wv = ((const float4*)w)[idx];
            bf16x4 o;
            o[0] = (bf16)v.x; o[1] = (bf16)v.y; o[2] = (bf16)v.z; o[3] = (bf16)v.w;
            ((bf16x4*)dst)[idx] = o;
            d += v.x * wv.x + v.y * wv.y + v.z * wv.z + v.w * wv.w;
        }
        #pragma unroll
        for (int off = 32; off > 0; off >>= 1)
            d += __shfl_down(d, off, 64);
        if (lane == 0) *sout = d;
    } else {
        __shared__ float tile[32][33];
        int t  = blk - 4096;
        int bx = (t & 31) * 32;
        int by = (t >> 5) * 32;
        int tx = threadIdx.x & 31;
        int ty4 = (threadIdx.x >> 5) * 4;
        #pragma unroll
        for (int i = 0; i < 4; ++i)
            tile[ty4 + i][tx] = U[(size_t)(by + ty4 + i) * D_DIM + bx + tx];
        __syncthreads();
        #pragma unroll
        for (int i = 0; i < 4; ++i)
            Ut[(size_t)(bx + ty4 + i) * D_DIM + by + tx] = (bf16)tile[tx][ty4 + i];
    }
}

// ---------------------------------------------------------------------------
// GEMM: C[m][n] = sum_k A[m][k] * Bt[n][k], K = 1024.
// R8: 64x128 tile -> grid 1024 = 4 blocks/CU (R2/R4/R5 all tied at 2
// blocks/CU regardless of pipelining: the barrier-drain stall needs
// INDEPENDENT blocks to overlap, not more waves in one barrier group).
// 256 thd = 4 waves in 1x4; each wave: 64 rows x 32 cols = acc[4][2].
// LDS 24 KB/block (A 8 KB + B 16 KB), __launch_bounds__(256,4).
// m97 2-barrier K-loop, width-16 global_load_lds, XOR-swizzled granules.
// EPI=0: bf16 store. EPI=1: fp32 + s_row + s_col + bias, nontemporal.
// ---------------------------------------------------------------------------
template <int EPI>
__global__ __launch_bounds__(256, 4) void gemm_bt_kernel(
    const bf16* __restrict__ A, const bf16* __restrict__ Bt,
    void* __restrict__ Cout,
    int N,
    long long sA, long long sB, long long sC,
    const float* __restrict__ s_row, const float* __restrict__ s_col,
    const float* __restrict__ bias)
{
    const int BK = 64;
    __shared__ bf16 As[64 * BK];           // 8 KB
    __shared__ bf16 Bs[128 * BK];          // 16 KB

    int tid  = threadIdx.x;
    int wid  = tid >> 6;       // 0..3 = wave col
    int lane = tid & 63;
    int quad = lane >> 4;
    int l16  = lane & 15;

    int tile_m = blockIdx.y * 64;
    int tile_n = blockIdx.x * 128;
    int bz     = blockIdx.z;

    const bf16* Ab = A  + (size_t)bz * sA + (size_t)tile_m * D_DIM;
    const bf16* Bb = Bt + (size_t)bz * sB + (size_t)tile_n * D_DIM;

    floatx4 zero = {0.0f, 0.0f, 0.0f, 0.0f};
    floatx4 acc[4][2];
    #pragma unroll
    for (int i = 0; i < 4; ++i)
        #pragma unroll
        for (int j = 0; j < 2; ++j) acc[i][j] = zero;

    for (int k0 = 0; k0 < D_DIM; k0 += BK) {
        // ---- stage A: 512 granules (2/thread); B: 1024 granules (4/thread)
        #pragma unroll
        for (int it = 0; it < 2; ++it) {
            int g  = wid * 128 + it * 64 + lane;     // 0..511
            int r  = g >> 3;                         // 0..63
            int cg = (g & 7) ^ (r & 7);
            int ldsoff = (wid * 128 + it * 64) * 8;
            async_copy16(Ab + (size_t)r * D_DIM + k0 + cg * 8, &As[ldsoff]);
        }
        #pragma unroll
        for (int it = 0; it < 4; ++it) {
            int g  = wid * 256 + it * 64 + lane;     // 0..1023
            int r  = g >> 3;                         // 0..127
            int cg = (g & 7) ^ (r & 7);
            int ldsoff = (wid * 256 + it * 64) * 8;
            async_copy16(Bb + (size_t)r * D_DIM + k0 + cg * 8, &Bs[ldsoff]);
        }
        __syncthreads();   // vmcnt(0) drain: staging complete

        #pragma unroll
        for (int kk = 0; kk < BK; kk += 32) {
            bf16x8 a[4], b[2];
            #pragma unroll
            for (int mt = 0; mt < 4; ++mt) {
                int row  = mt * 16 + l16;
                int slot = ((kk >> 3) + quad) ^ (row & 7);
                a[mt] = *(const bf16x8*)&As[row * BK + slot * 8];
            }
            #pragma unroll
            for (int nt = 0; nt < 2; ++nt) {
                int row  = wid * 32 + nt * 16 + l16;
                int slot = ((kk >> 3) + quad) ^ (row & 7);
                b[nt] = *(const bf16x8*)&Bs[row * BK + slot * 8];
            }
            #pragma unroll
            for (int mt = 0; mt < 4; ++mt)
                #pragma unroll
                for (int nt = 0; nt < 2; ++nt)
                    acc[mt][nt] = __builtin_amdgcn_mfma_f32_16x16x32_bf16(
                        a[mt], b[nt], acc[mt][nt], 0, 0, 0);
        }
        __syncthreads();   // all reads done before next-iter staging
    }

    // ---- epilogue: C/D layout col = lane&15, row = quad*4 + reg ----
    int row0 = tile_m;
    int col0 = tile_n + wid * 32;
    if (EPI == 0) {
        bf16* Cb = (bf16*)Cout + (size_t)bz * sC;
        #pragma unroll
        for (int mt = 0; mt < 4; ++mt)
            #pragma unroll
            for (int r = 0; r < 4; ++r) {
                int row = row0 + mt * 16 + quad * 4 + r;
                #pragma unroll
                for (int nt = 0; nt < 2; ++nt) {
                    int col = col0 + nt * 16 + l16;
                    Cb[(size_t)row * N + col] = (bf16)acc[mt][nt][r];
                }
            }
    } else {
        float* Cf = (float*)Cout + (size_t)bz * sC;
        float b0 = bias[0];
        const float* srow = s_row + (size_t)bz * S_DIM;
        const float* scol = s_col + (size_t)bz * S_DIM;
        #pragma unroll
        for (int mt = 0; mt < 4; ++mt)
            #pragma unroll
            for (int r = 0; r < 4; ++r) {
                int row = row0 + mt * 16 + quad * 4 + r;
                float sh = srow[row] + b0;
                #pragma unroll
                for (int nt = 0; nt < 2; ++nt) {
                    int col = col0 + nt * 16 + l16;
                    __builtin_nontemporal_store(acc[mt][nt][r] + sh + scol[col],
                                                &Cf[(size_t)row * N + col]);
                }
            }
    }
}

// ---------------------------------------------------------------------------
extern "C" void kernel_launch(void* const* d_in, const int* in_sizes, int n_in,
                              void* d_out, int out_size, void* d_ws, size_t ws_size,
                              hipStream_t stream) {
    const float* head   = (const float*)d_in[0];
    const float* dep    = (const float*)d_in[1];
    const float* edge_U = (const float*)d_in[2];
    const float* edge_W = (const float*)d_in[3];
    const float* edge_b = (const float*)d_in[4];
    float* out = (float*)d_out;

    char* ws = (char*)d_ws;
    const size_t nBSD = (size_t)B_DIM * S_DIM * D_DIM;

    bf16*  head_b = (bf16*)ws;  ws += nBSD * sizeof(bf16);
    bf16*  dep_b  = (bf16*)ws;  ws += nBSD * sizeof(bf16);
    bf16*  Ut     = (bf16*)ws;  ws += (size_t)D_DIM * D_DIM * sizeof(bf16);
    bf16*  tmp_b  = (bf16*)ws;  ws += nBSD * sizeof(bf16);
    float* s_head = (float*)ws; ws += (size_t)B_DIM * S_DIM * sizeof(float);
    float* s_dep  = (float*)ws; ws += (size_t)B_DIM * S_DIM * sizeof(float);

    // 1. fused cast+projection (4096 blocks) and U-transpose (1024 blocks)
    prep_kernel<<<4096 + 1024, 256, 0, stream>>>(
        head, dep, edge_U, edge_W, head_b, dep_b, Ut, s_head, s_dep);

    // 2. tmp[b,i,k] = head[b,i,:] @ U   ([8192 x 1024] x Ut^T), 64x128 tiles
    //    grid 8 x 128 = 1024 blocks = 4/CU; same-B blocks share an XCD (id%8)
    gemm_bt_kernel<0><<<dim3(D_DIM / 128, (B_DIM * S_DIM) / 64, 1), 256, 0, stream>>>(
        head_b, Ut, tmp_b, D_DIM,
        0, 0, 0, nullptr, nullptr, nullptr);

    // 3. out[b,i,j] = tmp[b,i,:] @ dep[b,j,:]^T + s_head + s_dep + bias
    //    grid 8 x 16 x 8 = 1024 blocks
    gemm_bt_kernel<1><<<dim3(S_DIM / 128, S_DIM / 64, B_DIM), 256, 0, stream>>>(
        tmp_b, dep_b, out, S_DIM,
        (long long)S_DIM * D_DIM, (long long)S_DIM * D_DIM,
        (long long)S_DIM * S_DIM,
        s_head, s_dep, edge_b);
}